// Round 6
// baseline (248.570 us; speedup 1.0000x reference)
//
#include <hip/hip_runtime.h>
#include <hip/hip_bf16.h>

#define D 512
#define T_ETYPES 8
#define NT_TYPES 4
#define K_MAIN 4096   // T_ETYPES * D
#define K_A 4608      // A row stride: 4096 msg cols + 512 root cols (type-specific)
#define K_B 6144      // WbT row stride: 4096 rel + 4*512 root windows
#define SPLITS 6
#define KSPLIT 768    // K_A / SPLITS (24 tiles of 32)

typedef __attribute__((ext_vector_type(8))) short bf16x8;
typedef __attribute__((ext_vector_type(4))) float f32x4;

__device__ __forceinline__ unsigned short f2bf(float f) {
    union { float f; unsigned u; } u{f};
    unsigned r = u.u + 0x7FFF + ((u.u >> 16) & 1);   // RNE
    return (unsigned short)(r >> 16);
}
__device__ __forceinline__ float bf2f(unsigned short h) {
    union { unsigned u; float f; } v{(unsigned)h << 16};
    return v.f;
}

// async global->LDS, 16B per lane (LDS dest must be wave-uniform base + lane*16)
__device__ __forceinline__ void gl16(const unsigned short* g, unsigned short* l) {
    __builtin_amdgcn_global_load_lds(
        (const __attribute__((address_space(1))) unsigned int*)g,
        (__attribute__((address_space(3))) unsigned int*)l,
        16, 0, 0);
}

// ---- one-time weight prep: WbT[o][c] = bf16( c<4096 ? rel_W[c/512][c%512][o]
//                                                      : root_W[(c-4096)/512][(c-4096)%512][o] )
__global__ void convert_weights(const float* __restrict__ relW,
                                const float* __restrict__ rootW,
                                unsigned short* __restrict__ WbT) {
    __shared__ float tile[32][33];
    int c0 = blockIdx.x * 32;
    int o0 = blockIdx.y * 32;
    int tid = threadIdx.x;
#pragma unroll
    for (int it = 0; it < 4; ++it) {
        int idx = it * 256 + tid;
        int oc = idx & 31, cc = idx >> 5;
        int c = c0 + cc, o = o0 + oc;
        float v = (c < K_MAIN) ? relW[(size_t)c * D + o]
                               : rootW[(size_t)(c - K_MAIN) * D + o];
        tile[cc][oc] = v;
    }
    __syncthreads();
#pragma unroll
    for (int it = 0; it < 4; ++it) {
        int idx = it * 256 + tid;
        int cc = idx & 31, oc = idx >> 5;
        WbT[(size_t)(o0 + oc) * K_B + (c0 + cc)] = f2bf(tile[cc][oc]);
    }
}

// ---- edge sort by seg = dst*8+etype: histogram -> scan -> scatter
__global__ void hist_kernel(const int* __restrict__ edst, const int* __restrict__ etyp,
                            int* __restrict__ counts, int E) {
    int e = blockIdx.x * 256 + threadIdx.x;
    if (e < E) atomicAdd(&counts[edst[e] * T_ETYPES + etyp[e]], 1);
}

__global__ void scan1(const int* __restrict__ counts, int* __restrict__ partial,
                      int* __restrict__ blockSums, int n) {
    __shared__ int sh[256];
    int tid = threadIdx.x, i = blockIdx.x * 256 + tid;
    int c = (i < n) ? counts[i] : 0;
    int val = c;
    sh[tid] = val; __syncthreads();
#pragma unroll
    for (int off = 1; off < 256; off <<= 1) {
        int add = (tid >= off) ? sh[tid - off] : 0;
        __syncthreads();
        val += add; sh[tid] = val;
        __syncthreads();
    }
    if (i < n) partial[i] = val - c;             // exclusive within block
    if (tid == 255) blockSums[blockIdx.x] = val; // block total
}

__global__ void scan2(int* __restrict__ blockSums, int nb) {
    __shared__ int sh[512];
    int tid = threadIdx.x;
    int c = (tid < nb) ? blockSums[tid] : 0;
    int val = c;
    sh[tid] = val; __syncthreads();
#pragma unroll
    for (int off = 1; off < 512; off <<= 1) {
        int add = (tid >= off) ? sh[tid - off] : 0;
        __syncthreads();
        val += add; sh[tid] = val;
        __syncthreads();
    }
    if (tid < nb) blockSums[tid] = val - c;      // exclusive block offsets
}

__global__ void scan3(const int* __restrict__ partial, const int* __restrict__ blockSums,
                      int* __restrict__ offsets, int* __restrict__ cursors, int n) {
    int i = blockIdx.x * 256 + threadIdx.x;
    if (i < n) {
        int v = partial[i] + blockSums[i >> 8];
        offsets[i] = v;
        cursors[i] = v;
    }
}

__global__ void scatter_kernel(const int* __restrict__ esrc, const int* __restrict__ edst,
                               const int* __restrict__ etyp, int* __restrict__ cursors,
                               int* __restrict__ perm, int E) {
    int e = blockIdx.x * 256 + threadIdx.x;
    if (e < E) {
        int seg = edst[e] * T_ETYPES + etyp[e];
        int pos = atomicAdd(&cursors[seg], 1);
        perm[pos] = esrc[e];
    }
}

// ---- target-node sort by type: histogram -> prep (aligned group starts) -> scatter
__global__ void thist(const int* __restrict__ tnt, int* __restrict__ tcnt, int M) {
    __shared__ int h[NT_TYPES];
    if (threadIdx.x < NT_TYPES) h[threadIdx.x] = 0;
    __syncthreads();
    int i = blockIdx.x * 256 + threadIdx.x;
    if (i < M) atomicAdd(&h[tnt[i]], 1);
    __syncthreads();
    if (threadIdx.x < NT_TYPES) atomicAdd(&tcnt[threadIdx.x], h[threadIdx.x]);
}

__global__ void tprep(const int* __restrict__ tcnt, int* __restrict__ gstart,
                      int* __restrict__ endv, int* __restrict__ tcur) {
    if (threadIdx.x == 0 && blockIdx.x == 0) {
        int s = 0;
        for (int g = 0; g < NT_TYPES; ++g) {
            gstart[g] = s; tcur[g] = s; endv[g] = s + tcnt[g];
            s += ((tcnt[g] + 127) >> 7) << 7;    // pad each group to 128-row blocks
        }
        gstart[NT_TYPES] = s;
    }
}

__global__ void tscatter(const int* __restrict__ tnt, int* __restrict__ tcur,
                         int* __restrict__ rowperm, int* __restrict__ invperm, int M) {
    int n = blockIdx.x * 256 + threadIdx.x;
    if (n < M) {
        int g = tnt[n];
        int p = atomicAdd(&tcur[g], 1);
        rowperm[p] = n;
        invperm[n] = p;
    }
}

// ---- segment mean, direct to bf16 A[invperm[dst]][etype*512 + k]; one wave per segment
__global__ void segmean(const float* __restrict__ x_src, const int* __restrict__ perm,
                        const int* __restrict__ offsets, const int* __restrict__ counts,
                        const int* __restrict__ invperm,
                        unsigned short* __restrict__ A, int nseg) {
    int seg = blockIdx.x * 4 + (threadIdx.x >> 6);
    if (seg >= nseg) return;
    int lane = threadIdx.x & 63;
    int beg = offsets[seg], cnt = counts[seg];
    float4 a0 = make_float4(0.f, 0.f, 0.f, 0.f);
    float4 a1 = make_float4(0.f, 0.f, 0.f, 0.f);
    for (int i = 0; i < cnt; ++i) {
        int s = perm[beg + i];
        const float4* p = reinterpret_cast<const float4*>(x_src + (size_t)s * D);
        float4 v0 = p[lane * 2], v1 = p[lane * 2 + 1];
        a0.x += v0.x; a0.y += v0.y; a0.z += v0.z; a0.w += v0.w;
        a1.x += v1.x; a1.y += v1.y; a1.z += v1.z; a1.w += v1.w;
    }
    float sc = (cnt > 0) ? 1.0f / (float)cnt : 0.0f;
    uint4 u;
    u.x = (unsigned)f2bf(a0.x * sc) | ((unsigned)f2bf(a0.y * sc) << 16);
    u.y = (unsigned)f2bf(a0.z * sc) | ((unsigned)f2bf(a0.w * sc) << 16);
    u.z = (unsigned)f2bf(a1.x * sc) | ((unsigned)f2bf(a1.y * sc) << 16);
    u.w = (unsigned)f2bf(a1.z * sc) | ((unsigned)f2bf(a1.w * sc) << 16);
    int dst = seg >> 3, t = seg & 7;
    int nrow = invperm[dst];
    *reinterpret_cast<uint4*>(A + (size_t)nrow * K_A + t * D + lane * 8) = u;
}

// ---- fill root slot: A[invperm[n]][4096 + k] = bf16(x_target[n][k])
__global__ void rootfill(const float* __restrict__ x_target, const int* __restrict__ invperm,
                         unsigned short* __restrict__ A, int M) {
    int idx = blockIdx.x * 256 + threadIdx.x;
    if (idx >= M * 64) return;
    int n = idx >> 6;
    int col = (idx & 63) * 8;
    const float4* p = reinterpret_cast<const float4*>(x_target + (size_t)n * D + col);
    float4 v0 = p[0], v1 = p[1];
    uint4 u;
    u.x = (unsigned)f2bf(v0.x) | ((unsigned)f2bf(v0.y) << 16);
    u.y = (unsigned)f2bf(v0.z) | ((unsigned)f2bf(v0.w) << 16);
    u.z = (unsigned)f2bf(v1.x) | ((unsigned)f2bf(v1.y) << 16);
    u.w = (unsigned)f2bf(v1.z) | ((unsigned)f2bf(v1.w) << 16);
    *reinterpret_cast<uint4*>(A + (size_t)invperm[n] * K_A + K_MAIN + col) = u;
}

// ---- split-K GEMM over type-sorted rows: pbuf[z][nrow][o] = sum_{c in split z} ...
// Each 128-row block is single-typed (groups 128-aligned): root phase uses only
// that type's 512-col B window -> K per block = 4608, not 6144.
// Single-buffer 2-barrier loop (round-4 structure; dbuf was neutral in round 5).
// 1D grid, XCD-chunk swizzle, A-panel-major logical order: l = ((z*MBP + m)*4 + n).
__global__ __launch_bounds__(256, 4)
void rgcn_gemm_sk(const unsigned short* __restrict__ A,
                  const unsigned short* __restrict__ WbT,
                  unsigned short* __restrict__ pbuf,
                  const int* __restrict__ gstart, const int* __restrict__ endv,
                  int MBP, int MPc) {
    __shared__ unsigned short As[128 * 32];
    __shared__ unsigned short Bs[128 * 32];
    const int tid = threadIdx.x;

    // swizzled logical id
    int d = blockIdx.x;
    int l = d;
    if ((gridDim.x & 7) == 0) {
        int cpx = gridDim.x >> 3;
        l = (d & 7) * cpx + (d >> 3);
    }
    const int nIdx = l & 3;
    const int mz = l >> 2;
    const int mIdx = mz % MBP;
    const int zIdx = mz / MBP;

    const int blockM = mIdx * 128;
    const int blockN = nIdx * 128;
    const int kBase = zIdx * KSPLIT;
    const int g = (blockM >= gstart[1]) + (blockM >= gstart[2]) + (blockM >= gstart[3]);
    const int endRow = endv[g];
    const int rootOff = g * 512;     // B-column window offset for root phase

    const int wid = tid >> 6, lane = tid & 63;
    const int wr = wid >> 1, wc = wid & 1;
    const int lr = lane & 15, lg = lane >> 4;

    f32x4 acc[4][4] = {};

    // staging chunk ids: chunk c (0..511) -> row c>>2, k-seg c&3
    const int c0 = tid, c1 = 256 + tid;
    const unsigned short* Abase = A + (size_t)blockM * K_A + kBase;
    const unsigned short* Bbase = WbT + (size_t)blockN * K_B;
    // NOTE: padding rows read garbage (mapped ws, deterministic-irrelevant);
    // their acc rows are never stored (MFMA rows are independent).

    for (int t = 0; t < KSPLIT / 32; ++t) {
        const int k0 = t * 32;
        const int kc = kBase + k0;
        const int bc = (kc < K_MAIN) ? kc : kc + rootOff;   // uniform per tile (4096%32==0)
        gl16(Abase + (size_t)(c0 >> 2) * K_A + k0 + (c0 & 3) * 8, &As[c0 * 8]);
        gl16(Abase + (size_t)(c1 >> 2) * K_A + k0 + (c1 & 3) * 8, &As[c1 * 8]);
        gl16(Bbase + (size_t)(c0 >> 2) * K_B + bc + (c0 & 3) * 8, &Bs[c0 * 8]);
        gl16(Bbase + (size_t)(c1 >> 2) * K_B + bc + (c1 & 3) * 8, &Bs[c1 * 8]);
        __syncthreads();

        bf16x8 a_frag[4], b_frag[4];
#pragma unroll
        for (int mi = 0; mi < 4; ++mi)
            a_frag[mi] = *reinterpret_cast<const bf16x8*>(&As[(wr * 64 + mi * 16 + lr) * 32 + lg * 8]);
#pragma unroll
        for (int ni = 0; ni < 4; ++ni)
            b_frag[ni] = *reinterpret_cast<const bf16x8*>(&Bs[(wc * 64 + ni * 16 + lr) * 32 + lg * 8]);
#pragma unroll
        for (int mi = 0; mi < 4; ++mi)
#pragma unroll
            for (int ni = 0; ni < 4; ++ni)
                acc[mi][ni] = __builtin_amdgcn_mfma_f32_16x16x32_bf16(a_frag[mi], b_frag[ni], acc[mi][ni], 0, 0, 0);
        __syncthreads();
    }

    // epilogue: bf16 partial per split (skip padding rows)
#pragma unroll
    for (int mi = 0; mi < 4; ++mi) {
#pragma unroll
        for (int r = 0; r < 4; ++r) {
            int row = blockM + wr * 64 + mi * 16 + lg * 4 + r;
            if (row < endRow) {
#pragma unroll
                for (int ni = 0; ni < 4; ++ni) {
                    int col = blockN + wc * 64 + ni * 16 + lr;
                    pbuf[((size_t)zIdx * MPc + row) * D + col] = f2bf(acc[mi][ni][r]);
                }
            }
        }
    }
}

// ---- reduce splits + per-type bias -> f32 out (un-permute rows)
__global__ void reduce_bias(const unsigned short* __restrict__ pbuf,
                            const int* __restrict__ rowperm, const int* __restrict__ tnt,
                            const float* __restrict__ root_b,
                            float* __restrict__ out, int MPc) {
    int idx = blockIdx.x * 256 + threadIdx.x;   // one per 8 outputs
    if (idx >= MPc * 64) return;
    int nrow = idx >> 6;
    int col = (idx & 63) * 8;
    int orig = rowperm[nrow];
    if (orig < 0) return;
    float s[8] = {0.f, 0.f, 0.f, 0.f, 0.f, 0.f, 0.f, 0.f};
#pragma unroll
    for (int sp = 0; sp < SPLITS; ++sp) {
        uint4 v = *reinterpret_cast<const uint4*>(pbuf + ((size_t)sp * MPc + nrow) * D + col);
        unsigned u[4] = {v.x, v.y, v.z, v.w};
#pragma unroll
        for (int j = 0; j < 4; ++j) {
            s[2 * j]     += bf2f((unsigned short)(u[j] & 0xFFFF));
            s[2 * j + 1] += bf2f((unsigned short)(u[j] >> 16));
        }
    }
    const float* b = root_b + (size_t)tnt[orig] * D + col;
    float4 o0, o1;
    o0.x = s[0] + b[0]; o0.y = s[1] + b[1]; o0.z = s[2] + b[2]; o0.w = s[3] + b[3];
    o1.x = s[4] + b[4]; o1.y = s[5] + b[5]; o1.z = s[6] + b[6]; o1.w = s[7] + b[7];
    float* o = out + (size_t)orig * D + col;
    *reinterpret_cast<float4*>(o) = o0;
    *reinterpret_cast<float4*>(o + 4) = o1;
}

extern "C" void kernel_launch(void* const* d_in, const int* in_sizes, int n_in,
                              void* d_out, int out_size, void* d_ws, size_t ws_size,
                              hipStream_t stream) {
    const float* x_src    = (const float*)d_in[0];
    const float* x_target = (const float*)d_in[1];
    const float* relW     = (const float*)d_in[2];
    const float* rootW    = (const float*)d_in[3];
    const float* rootb    = (const float*)d_in[4];
    const int*   esrc     = (const int*)d_in[5];
    const int*   edst     = (const int*)d_in[6];
    const int*   etyp     = (const int*)d_in[7];
    const int*   tnt      = (const int*)d_in[8];
    float* out = (float*)d_out;

    const int E = in_sizes[5];
    const int M = in_sizes[8];               // n_tgt = 10000
    const int NSEG = M * T_ETYPES;           // 80000
    const int NB = (NSEG + 255) / 256;       // 313
    const int MBP = (M + 127) / 128 + (NT_TYPES - 1);  // 82 (worst-case padded blocks)
    const int MPc = MBP * 128;               // 10496 padded rows

    char* ws = (char*)d_ws;
    size_t off = 0;
    unsigned short* Abf = (unsigned short*)(ws + off); off += (size_t)MPc * K_A * 2;        // 96.7 MB
    unsigned short* WbT = (unsigned short*)(ws + off); off += (size_t)D * K_B * 2;          // 6.29 MB
    unsigned short* pb  = (unsigned short*)(ws + off); off += (size_t)SPLITS * MPc * D * 2; // 64.5 MB
    int* counts    = (int*)(ws + off); off += (size_t)NSEG * 4;
    int* tcnt      = (int*)(ws + off); off += NT_TYPES * 4;          // memset'd with counts
    int* partial   = (int*)(ws + off); off += (size_t)NSEG * 4;
    int* offsets   = (int*)(ws + off); off += (size_t)NSEG * 4;
    int* cursors   = (int*)(ws + off); off += (size_t)NSEG * 4;
    int* blockSums = (int*)(ws + off); off += 512 * 4;
    int* perm      = (int*)(ws + off); off += (size_t)E * 4;
    int* gstart    = (int*)(ws + off); off += 8 * 4;                 // [5] used
    int* endv      = (int*)(ws + off); off += 8 * 4;                 // [4] used
    int* tcur      = (int*)(ws + off); off += 8 * 4;                 // [4] used
    int* rowperm   = (int*)(ws + off); off += (size_t)MPc * 4;       // memset 0xFF
    int* invperm   = (int*)(ws + off); off += (size_t)M * 4;

    hipMemsetAsync(counts, 0, ((size_t)NSEG + NT_TYPES) * 4, stream);
    hipMemsetAsync(rowperm, 0xFF, (size_t)MPc * 4, stream);

    convert_weights<<<dim3(K_B / 32, D / 32), 256, 0, stream>>>(relW, rootW, WbT);
    // target sort by type
    thist<<<(M + 255) / 256, 256, 0, stream>>>(tnt, tcnt, M);
    tprep<<<1, 64, 0, stream>>>(tcnt, gstart, endv, tcur);
    tscatter<<<(M + 255) / 256, 256, 0, stream>>>(tnt, tcur, rowperm, invperm, M);
    // edge sort by (dst, etype)
    hist_kernel<<<(E + 255) / 256, 256, 0, stream>>>(edst, etyp, counts, E);
    scan1<<<NB, 256, 0, stream>>>(counts, partial, blockSums, NSEG);
    scan2<<<1, 512, 0, stream>>>(blockSums, NB);
    scan3<<<NB, 256, 0, stream>>>(partial, blockSums, offsets, cursors, NSEG);
    scatter_kernel<<<(E + 255) / 256, 256, 0, stream>>>(esrc, edst, etyp, cursors, perm, E);
    // build A (type-sorted rows)
    segmean<<<(NSEG + 3) / 4, 256, 0, stream>>>(x_src, perm, offsets, counts, invperm, Abf, NSEG);
    rootfill<<<(M * 64 + 255) / 256, 256, 0, stream>>>(x_target, invperm, Abf, M);
    // GEMM + reduce
    rgcn_gemm_sk<<<MBP * 4 * SPLITS, 256, 0, stream>>>(Abf, WbT, pb, gstart, endv, MBP, MPc);
    reduce_bias<<<(MPc * 64 + 255) / 256, 256, 0, stream>>>(pb, rowperm, tnt, rootb, out, MPc);
}

// Round 7
// 195.658 us; speedup vs baseline: 1.2704x; 1.2704x over previous
//
#include <hip/hip_runtime.h>
#include <hip/hip_bf16.h>

#define D 512
#define T_ETYPES 8
#define NT_TYPES 4
#define K_MAIN 4096   // T_ETYPES * D
#define K_A 4608      // A row stride: 4096 msg cols + 512 root cols (type-specific)
#define K_B 6144      // WbT row stride: 4096 rel + 4*512 root windows
#define SPLITS 6
#define KSPLIT 768    // K_A / SPLITS (24 tiles of 32)

typedef __attribute__((ext_vector_type(8))) short bf16x8;
typedef __attribute__((ext_vector_type(4))) float f32x4;

__device__ __forceinline__ unsigned short f2bf(float f) {
    union { float f; unsigned u; } u{f};
    unsigned r = u.u + 0x7FFF + ((u.u >> 16) & 1);   // RNE
    return (unsigned short)(r >> 16);
}
__device__ __forceinline__ float bf2f(unsigned short h) {
    union { unsigned u; float f; } v{(unsigned)h << 16};
    return v.f;
}

// async global->LDS, 16B per lane (LDS dest must be wave-uniform base + lane*16)
__device__ __forceinline__ void gl16(const unsigned short* g, unsigned short* l) {
    __builtin_amdgcn_global_load_lds(
        (const __attribute__((address_space(1))) unsigned int*)g,
        (__attribute__((address_space(3))) unsigned int*)l,
        16, 0, 0);
}

// ---- one-time weight prep: WbT[o][c] = bf16( c<4096 ? rel_W[c/512][c%512][o]
//                                                      : root_W[(c-4096)/512][(c-4096)%512][o] )
__global__ void convert_weights(const float* __restrict__ relW,
                                const float* __restrict__ rootW,
                                unsigned short* __restrict__ WbT) {
    __shared__ float tile[32][33];
    int c0 = blockIdx.x * 32;
    int o0 = blockIdx.y * 32;
    int tid = threadIdx.x;
#pragma unroll
    for (int it = 0; it < 4; ++it) {
        int idx = it * 256 + tid;
        int oc = idx & 31, cc = idx >> 5;
        int c = c0 + cc, o = o0 + oc;
        float v = (c < K_MAIN) ? relW[(size_t)c * D + o]
                               : rootW[(size_t)(c - K_MAIN) * D + o];
        tile[cc][oc] = v;
    }
    __syncthreads();
#pragma unroll
    for (int it = 0; it < 4; ++it) {
        int idx = it * 256 + tid;
        int cc = idx & 31, oc = idx >> 5;
        WbT[(size_t)(o0 + oc) * K_B + (c0 + cc)] = f2bf(tile[cc][oc]);
    }
}

// ---- edge sort by seg = dst*8+etype: histogram -> scan -> scatter
__global__ void hist_kernel(const int* __restrict__ edst, const int* __restrict__ etyp,
                            int* __restrict__ counts, int E) {
    int e = blockIdx.x * 256 + threadIdx.x;
    if (e < E) atomicAdd(&counts[edst[e] * T_ETYPES + etyp[e]], 1);
}

__global__ void scan1(const int* __restrict__ counts, int* __restrict__ partial,
                      int* __restrict__ blockSums, int n) {
    __shared__ int sh[256];
    int tid = threadIdx.x, i = blockIdx.x * 256 + tid;
    int c = (i < n) ? counts[i] : 0;
    int val = c;
    sh[tid] = val; __syncthreads();
#pragma unroll
    for (int off = 1; off < 256; off <<= 1) {
        int add = (tid >= off) ? sh[tid - off] : 0;
        __syncthreads();
        val += add; sh[tid] = val;
        __syncthreads();
    }
    if (i < n) partial[i] = val - c;             // exclusive within block
    if (tid == 255) blockSums[blockIdx.x] = val; // block total
}

__global__ void scan2(int* __restrict__ blockSums, int nb) {
    __shared__ int sh[512];
    int tid = threadIdx.x;
    int c = (tid < nb) ? blockSums[tid] : 0;
    int val = c;
    sh[tid] = val; __syncthreads();
#pragma unroll
    for (int off = 1; off < 512; off <<= 1) {
        int add = (tid >= off) ? sh[tid - off] : 0;
        __syncthreads();
        val += add; sh[tid] = val;
        __syncthreads();
    }
    if (tid < nb) blockSums[tid] = val - c;      // exclusive block offsets
}

__global__ void scan3(const int* __restrict__ partial, const int* __restrict__ blockSums,
                      int* __restrict__ offsets, int* __restrict__ cursors, int n) {
    int i = blockIdx.x * 256 + threadIdx.x;
    if (i < n) {
        int v = partial[i] + blockSums[i >> 8];
        offsets[i] = v;
        cursors[i] = v;
    }
}

__global__ void scatter_kernel(const int* __restrict__ esrc, const int* __restrict__ edst,
                               const int* __restrict__ etyp, int* __restrict__ cursors,
                               int* __restrict__ perm, int E) {
    int e = blockIdx.x * 256 + threadIdx.x;
    if (e < E) {
        int seg = edst[e] * T_ETYPES + etyp[e];
        int pos = atomicAdd(&cursors[seg], 1);
        perm[pos] = esrc[e];
    }
}

// ---- contention-free target-node sort by type (block-ranked counting sort)
__global__ void thist2(const int* __restrict__ tnt, int* __restrict__ bcnt, int M) {
    __shared__ int h[NT_TYPES];
    if (threadIdx.x < NT_TYPES) h[threadIdx.x] = 0;
    __syncthreads();
    int i = blockIdx.x * 256 + threadIdx.x;
    if (i < M) atomicAdd(&h[tnt[i]], 1);
    __syncthreads();
    if (threadIdx.x < NT_TYPES) bcnt[blockIdx.x * NT_TYPES + threadIdx.x] = h[threadIdx.x];
}

// tprep2: one block; totals -> 128-aligned group starts -> per-block offsets (all in LDS)
__global__ void tprep2(const int* __restrict__ bcnt, int nb,
                       int* __restrict__ boff, int* __restrict__ gstart,
                       int* __restrict__ endv) {
    __shared__ int sb[128 * NT_TYPES];
    __shared__ int gs[NT_TYPES];
    int tid = threadIdx.x;
    for (int i = tid; i < nb * NT_TYPES; i += blockDim.x) sb[i] = bcnt[i];
    __syncthreads();
    if (tid == 0) {
        int s = 0;
        for (int g = 0; g < NT_TYPES; ++g) {
            int tot = 0;
            for (int b = 0; b < nb; ++b) tot += sb[b * NT_TYPES + g];
            gs[g] = s;
            gstart[g] = s;
            endv[g] = s + tot;
            s += ((tot + 127) >> 7) << 7;     // pad each group to 128-row blocks
        }
        gstart[NT_TYPES] = s;
    }
    __syncthreads();
    if (tid < NT_TYPES) {
        int run = gs[tid];
        for (int b = 0; b < nb; ++b) {
            boff[b * NT_TYPES + tid] = run;
            run += sb[b * NT_TYPES + tid];
        }
    }
}

// tscatter2: local rank via LDS atomics + per-block offset. Any bijection is a
// valid assignment (output values are row-placement-invariant; un-permuted via rowperm).
__global__ void tscatter2(const int* __restrict__ tnt, const int* __restrict__ boff,
                          int* __restrict__ rowperm, int* __restrict__ invperm, int M) {
    __shared__ int h[NT_TYPES];
    if (threadIdx.x < NT_TYPES) h[threadIdx.x] = 0;
    __syncthreads();
    int n = blockIdx.x * 256 + threadIdx.x;
    if (n < M) {
        int g = tnt[n];
        int lr = atomicAdd(&h[g], 1);
        int p = boff[blockIdx.x * NT_TYPES + g] + lr;
        rowperm[p] = n;
        invperm[n] = p;
    }
}

// ---- segment mean, direct to bf16 A[invperm[dst]][etype*512 + k]; one wave per segment
__global__ void segmean(const float* __restrict__ x_src, const int* __restrict__ perm,
                        const int* __restrict__ offsets, const int* __restrict__ counts,
                        const int* __restrict__ invperm,
                        unsigned short* __restrict__ A, int nseg) {
    int seg = blockIdx.x * 4 + (threadIdx.x >> 6);
    if (seg >= nseg) return;
    int lane = threadIdx.x & 63;
    int beg = offsets[seg], cnt = counts[seg];
    float4 a0 = make_float4(0.f, 0.f, 0.f, 0.f);
    float4 a1 = make_float4(0.f, 0.f, 0.f, 0.f);
    for (int i = 0; i < cnt; ++i) {
        int s = perm[beg + i];
        const float4* p = reinterpret_cast<const float4*>(x_src + (size_t)s * D);
        float4 v0 = p[lane * 2], v1 = p[lane * 2 + 1];
        a0.x += v0.x; a0.y += v0.y; a0.z += v0.z; a0.w += v0.w;
        a1.x += v1.x; a1.y += v1.y; a1.z += v1.z; a1.w += v1.w;
    }
    float sc = (cnt > 0) ? 1.0f / (float)cnt : 0.0f;
    uint4 u;
    u.x = (unsigned)f2bf(a0.x * sc) | ((unsigned)f2bf(a0.y * sc) << 16);
    u.y = (unsigned)f2bf(a0.z * sc) | ((unsigned)f2bf(a0.w * sc) << 16);
    u.z = (unsigned)f2bf(a1.x * sc) | ((unsigned)f2bf(a1.y * sc) << 16);
    u.w = (unsigned)f2bf(a1.z * sc) | ((unsigned)f2bf(a1.w * sc) << 16);
    int dst = seg >> 3, t = seg & 7;
    int nrow = invperm[dst];
    *reinterpret_cast<uint4*>(A + (size_t)nrow * K_A + t * D + lane * 8) = u;
}

// ---- fill root slot: A[invperm[n]][4096 + k] = bf16(x_target[n][k])
__global__ void rootfill(const float* __restrict__ x_target, const int* __restrict__ invperm,
                         unsigned short* __restrict__ A, int M) {
    int idx = blockIdx.x * 256 + threadIdx.x;
    if (idx >= M * 64) return;
    int n = idx >> 6;
    int col = (idx & 63) * 8;
    const float4* p = reinterpret_cast<const float4*>(x_target + (size_t)n * D + col);
    float4 v0 = p[0], v1 = p[1];
    uint4 u;
    u.x = (unsigned)f2bf(v0.x) | ((unsigned)f2bf(v0.y) << 16);
    u.y = (unsigned)f2bf(v0.z) | ((unsigned)f2bf(v0.w) << 16);
    u.z = (unsigned)f2bf(v1.x) | ((unsigned)f2bf(v1.y) << 16);
    u.w = (unsigned)f2bf(v1.z) | ((unsigned)f2bf(v1.w) << 16);
    *reinterpret_cast<uint4*>(A + (size_t)invperm[n] * K_A + K_MAIN + col) = u;
}

// ---- split-K GEMM over type-sorted rows (single-typed 128-row blocks, K=4608)
__global__ __launch_bounds__(256, 4)
void rgcn_gemm_sk(const unsigned short* __restrict__ A,
                  const unsigned short* __restrict__ WbT,
                  unsigned short* __restrict__ pbuf,
                  const int* __restrict__ gstart, const int* __restrict__ endv,
                  int MBP, int MPc) {
    __shared__ unsigned short As[128 * 32];
    __shared__ unsigned short Bs[128 * 32];
    const int tid = threadIdx.x;

    int d = blockIdx.x;
    int l = d;
    if ((gridDim.x & 7) == 0) {
        int cpx = gridDim.x >> 3;
        l = (d & 7) * cpx + (d >> 3);
    }
    const int nIdx = l & 3;
    const int mz = l >> 2;
    const int mIdx = mz % MBP;
    const int zIdx = mz / MBP;

    const int blockM = mIdx * 128;
    const int blockN = nIdx * 128;
    const int kBase = zIdx * KSPLIT;
    const int g = (blockM >= gstart[1]) + (blockM >= gstart[2]) + (blockM >= gstart[3]);
    const int endRow = endv[g];
    const int rootOff = g * 512;

    const int wid = tid >> 6, lane = tid & 63;
    const int wr = wid >> 1, wc = wid & 1;
    const int lr = lane & 15, lg = lane >> 4;

    f32x4 acc[4][4] = {};

    const int c0 = tid, c1 = 256 + tid;
    const unsigned short* Abase = A + (size_t)blockM * K_A + kBase;
    const unsigned short* Bbase = WbT + (size_t)blockN * K_B;

    for (int t = 0; t < KSPLIT / 32; ++t) {
        const int k0 = t * 32;
        const int kc = kBase + k0;
        const int bc = (kc < K_MAIN) ? kc : kc + rootOff;   // uniform per tile
        gl16(Abase + (size_t)(c0 >> 2) * K_A + k0 + (c0 & 3) * 8, &As[c0 * 8]);
        gl16(Abase + (size_t)(c1 >> 2) * K_A + k0 + (c1 & 3) * 8, &As[c1 * 8]);
        gl16(Bbase + (size_t)(c0 >> 2) * K_B + bc + (c0 & 3) * 8, &Bs[c0 * 8]);
        gl16(Bbase + (size_t)(c1 >> 2) * K_B + bc + (c1 & 3) * 8, &Bs[c1 * 8]);
        __syncthreads();

        bf16x8 a_frag[4], b_frag[4];
#pragma unroll
        for (int mi = 0; mi < 4; ++mi)
            a_frag[mi] = *reinterpret_cast<const bf16x8*>(&As[(wr * 64 + mi * 16 + lr) * 32 + lg * 8]);
#pragma unroll
        for (int ni = 0; ni < 4; ++ni)
            b_frag[ni] = *reinterpret_cast<const bf16x8*>(&Bs[(wc * 64 + ni * 16 + lr) * 32 + lg * 8]);
#pragma unroll
        for (int mi = 0; mi < 4; ++mi)
#pragma unroll
            for (int ni = 0; ni < 4; ++ni)
                acc[mi][ni] = __builtin_amdgcn_mfma_f32_16x16x32_bf16(a_frag[mi], b_frag[ni], acc[mi][ni], 0, 0, 0);
        __syncthreads();
    }

#pragma unroll
    for (int mi = 0; mi < 4; ++mi) {
#pragma unroll
        for (int r = 0; r < 4; ++r) {
            int row = blockM + wr * 64 + mi * 16 + lg * 4 + r;
            if (row < endRow) {
#pragma unroll
                for (int ni = 0; ni < 4; ++ni) {
                    int col = blockN + wc * 64 + ni * 16 + lr;
                    pbuf[((size_t)zIdx * MPc + row) * D + col] = f2bf(acc[mi][ni][r]);
                }
            }
        }
    }
}

// ---- reduce splits + per-type bias -> f32 out (un-permute rows)
__global__ void reduce_bias(const unsigned short* __restrict__ pbuf,
                            const int* __restrict__ rowperm, const int* __restrict__ tnt,
                            const float* __restrict__ root_b,
                            float* __restrict__ out, int MPc) {
    int idx = blockIdx.x * 256 + threadIdx.x;   // one per 8 outputs
    if (idx >= MPc * 64) return;
    int nrow = idx >> 6;
    int col = (idx & 63) * 8;
    int orig = rowperm[nrow];
    if (orig < 0) return;
    float s[8] = {0.f, 0.f, 0.f, 0.f, 0.f, 0.f, 0.f, 0.f};
#pragma unroll
    for (int sp = 0; sp < SPLITS; ++sp) {
        uint4 v = *reinterpret_cast<const uint4*>(pbuf + ((size_t)sp * MPc + nrow) * D + col);
        unsigned u[4] = {v.x, v.y, v.z, v.w};
#pragma unroll
        for (int j = 0; j < 4; ++j) {
            s[2 * j]     += bf2f((unsigned short)(u[j] & 0xFFFF));
            s[2 * j + 1] += bf2f((unsigned short)(u[j] >> 16));
        }
    }
    const float* b = root_b + (size_t)tnt[orig] * D + col;
    float4 o0, o1;
    o0.x = s[0] + b[0]; o0.y = s[1] + b[1]; o0.z = s[2] + b[2]; o0.w = s[3] + b[3];
    o1.x = s[4] + b[4]; o1.y = s[5] + b[5]; o1.z = s[6] + b[6]; o1.w = s[7] + b[7];
    float* o = out + (size_t)orig * D + col;
    *reinterpret_cast<float4*>(o) = o0;
    *reinterpret_cast<float4*>(o + 4) = o1;
}

extern "C" void kernel_launch(void* const* d_in, const int* in_sizes, int n_in,
                              void* d_out, int out_size, void* d_ws, size_t ws_size,
                              hipStream_t stream) {
    const float* x_src    = (const float*)d_in[0];
    const float* x_target = (const float*)d_in[1];
    const float* relW     = (const float*)d_in[2];
    const float* rootW    = (const float*)d_in[3];
    const float* rootb    = (const float*)d_in[4];
    const int*   esrc     = (const int*)d_in[5];
    const int*   edst     = (const int*)d_in[6];
    const int*   etyp     = (const int*)d_in[7];
    const int*   tnt      = (const int*)d_in[8];
    float* out = (float*)d_out;

    const int E = in_sizes[5];
    const int M = in_sizes[8];               // n_tgt = 10000
    const int NSEG = M * T_ETYPES;           // 80000
    const int NB = (NSEG + 255) / 256;       // 313
    const int NBT = (M + 255) / 256;         // 40
    const int MBP = (M + 127) / 128 + (NT_TYPES - 1);  // 82
    const int MPc = MBP * 128;               // 10496

    char* ws = (char*)d_ws;
    size_t off = 0;
    unsigned short* Abf = (unsigned short*)(ws + off); off += (size_t)MPc * K_A * 2;        // 96.7 MB
    unsigned short* WbT = (unsigned short*)(ws + off); off += (size_t)D * K_B * 2;          // 6.29 MB
    unsigned short* pb  = (unsigned short*)(ws + off); off += (size_t)SPLITS * MPc * D * 2; // 64.5 MB
    int* counts    = (int*)(ws + off); off += (size_t)NSEG * 4;
    int* partial   = (int*)(ws + off); off += (size_t)NSEG * 4;
    int* offsets   = (int*)(ws + off); off += (size_t)NSEG * 4;
    int* cursors   = (int*)(ws + off); off += (size_t)NSEG * 4;
    int* blockSums = (int*)(ws + off); off += 512 * 4;
    int* perm      = (int*)(ws + off); off += (size_t)E * 4;
    int* bcnt      = (int*)(ws + off); off += (size_t)NBT * NT_TYPES * 4;
    int* boff      = (int*)(ws + off); off += (size_t)NBT * NT_TYPES * 4;
    int* gstart    = (int*)(ws + off); off += 8 * 4;
    int* endv      = (int*)(ws + off); off += 8 * 4;
    int* rowperm   = (int*)(ws + off); off += (size_t)MPc * 4;
    int* invperm   = (int*)(ws + off); off += (size_t)M * 4;

    hipMemsetAsync(counts, 0, (size_t)NSEG * 4, stream);
    hipMemsetAsync(rowperm, 0xFF, (size_t)MPc * 4, stream);

    convert_weights<<<dim3(K_B / 32, D / 32), 256, 0, stream>>>(relW, rootW, WbT);
    // target sort by type (contention-free)
    thist2<<<NBT, 256, 0, stream>>>(tnt, bcnt, M);
    tprep2<<<1, 256, 0, stream>>>(bcnt, NBT, boff, gstart, endv);
    tscatter2<<<NBT, 256, 0, stream>>>(tnt, boff, rowperm, invperm, M);
    // edge sort by (dst, etype)
    hist_kernel<<<(E + 255) / 256, 256, 0, stream>>>(edst, etyp, counts, E);
    scan1<<<NB, 256, 0, stream>>>(counts, partial, blockSums, NSEG);
    scan2<<<1, 512, 0, stream>>>(blockSums, NB);
    scan3<<<NB, 256, 0, stream>>>(partial, blockSums, offsets, cursors, NSEG);
    scatter_kernel<<<(E + 255) / 256, 256, 0, stream>>>(esrc, edst, etyp, cursors, perm, E);
    // build A (type-sorted rows)
    segmean<<<(NSEG + 3) / 4, 256, 0, stream>>>(x_src, perm, offsets, counts, invperm, Abf, NSEG);
    rootfill<<<(M * 64 + 255) / 256, 256, 0, stream>>>(x_target, invperm, Abf, M);
    // GEMM + reduce
    rgcn_gemm_sk<<<MBP * 4 * SPLITS, 256, 0, stream>>>(Abf, WbT, pb, gstart, endv, MBP, MPc);
    reduce_bias<<<(MPc * 64 + 255) / 256, 256, 0, stream>>>(pb, rowperm, tnt, rootb, out, MPc);
}

// Round 8
// 186.844 us; speedup vs baseline: 1.3304x; 1.0472x over previous
//
#include <hip/hip_runtime.h>
#include <hip/hip_bf16.h>

#define D 512
#define T_ETYPES 8
#define NT_TYPES 4
#define K_MAIN 4096   // T_ETYPES * D
#define K_A 4608      // A row stride: 4096 msg cols + 512 root cols (type-specific)
#define K_B 6144      // WbT row stride: 4096 rel + 4*512 root windows
#define SPLITS 6
#define KSPLIT 768    // K_A / SPLITS (12 tiles of 64)
#define BK 64         // K-tile per barrier

// Swizzle: within each aligned 64-col (128B) tile of a row, the 16B chunk with
// logical index j (0..7) is stored at position j ^ (row & 7). Producers
// (segmean/rootfill/convert_weights) write swizzled; global_load_lds copies
// linearly; the GEMM fragment read applies the same XOR. (rule #21: linear
// LDS dest + inverse-swizzled source + swizzle on read.)

typedef __attribute__((ext_vector_type(8))) short bf16x8;
typedef __attribute__((ext_vector_type(4))) float f32x4;

__device__ __forceinline__ unsigned short f2bf(float f) {
    union { float f; unsigned u; } u{f};
    unsigned r = u.u + 0x7FFF + ((u.u >> 16) & 1);   // RNE
    return (unsigned short)(r >> 16);
}
__device__ __forceinline__ float bf2f(unsigned short h) {
    union { unsigned u; float f; } v{(unsigned)h << 16};
    return v.f;
}

// async global->LDS, 16B per lane (LDS dest must be wave-uniform base + lane*16)
__device__ __forceinline__ void gl16(const unsigned short* g, unsigned short* l) {
    __builtin_amdgcn_global_load_lds(
        (const __attribute__((address_space(1))) unsigned int*)g,
        (__attribute__((address_space(3))) unsigned int*)l,
        16, 0, 0);
}

// ---- one-time weight prep (swizzled store): logical WbT[o][c]
__global__ void convert_weights(const float* __restrict__ relW,
                                const float* __restrict__ rootW,
                                unsigned short* __restrict__ WbT) {
    __shared__ float tile[32][33];
    int c0 = blockIdx.x * 32;
    int o0 = blockIdx.y * 32;
    int tid = threadIdx.x;
#pragma unroll
    for (int it = 0; it < 4; ++it) {
        int idx = it * 256 + tid;
        int oc = idx & 31, cc = idx >> 5;
        int c = c0 + cc, o = o0 + oc;
        float v = (c < K_MAIN) ? relW[(size_t)c * D + o]
                               : rootW[(size_t)(c - K_MAIN) * D + o];
        tile[cc][oc] = v;
    }
    __syncthreads();
#pragma unroll
    for (int it = 0; it < 4; ++it) {
        int idx = it * 256 + tid;
        int cc = idx & 31, oc = idx >> 5;
        int o = o0 + oc, c = c0 + cc;
        // swizzled column: chunk j=(c>>3)&7 -> j^(o&7) within the 64-col tile
        int csw = (c & ~63) | (((((c >> 3) & 7) ^ (o & 7))) << 3) | (c & 7);
        WbT[(size_t)o * K_B + csw] = f2bf(tile[cc][oc]);
    }
}

// ---- edge sort by seg = dst*8+etype: histogram -> scan -> scatter
__global__ void hist_kernel(const int* __restrict__ edst, const int* __restrict__ etyp,
                            int* __restrict__ counts, int E) {
    int e = blockIdx.x * 256 + threadIdx.x;
    if (e < E) atomicAdd(&counts[edst[e] * T_ETYPES + etyp[e]], 1);
}

__global__ void scan1(const int* __restrict__ counts, int* __restrict__ partial,
                      int* __restrict__ blockSums, int n) {
    __shared__ int sh[256];
    int tid = threadIdx.x, i = blockIdx.x * 256 + tid;
    int c = (i < n) ? counts[i] : 0;
    int val = c;
    sh[tid] = val; __syncthreads();
#pragma unroll
    for (int off = 1; off < 256; off <<= 1) {
        int add = (tid >= off) ? sh[tid - off] : 0;
        __syncthreads();
        val += add; sh[tid] = val;
        __syncthreads();
    }
    if (i < n) partial[i] = val - c;             // exclusive within block
    if (tid == 255) blockSums[blockIdx.x] = val; // block total
}

__global__ void scan2(int* __restrict__ blockSums, int nb) {
    __shared__ int sh[512];
    int tid = threadIdx.x;
    int c = (tid < nb) ? blockSums[tid] : 0;
    int val = c;
    sh[tid] = val; __syncthreads();
#pragma unroll
    for (int off = 1; off < 512; off <<= 1) {
        int add = (tid >= off) ? sh[tid - off] : 0;
        __syncthreads();
        val += add; sh[tid] = val;
        __syncthreads();
    }
    if (tid < nb) blockSums[tid] = val - c;      // exclusive block offsets
}

__global__ void scan3(const int* __restrict__ partial, const int* __restrict__ blockSums,
                      int* __restrict__ offsets, int* __restrict__ cursors, int n) {
    int i = blockIdx.x * 256 + threadIdx.x;
    if (i < n) {
        int v = partial[i] + blockSums[i >> 8];
        offsets[i] = v;
        cursors[i] = v;
    }
}

__global__ void scatter_kernel(const int* __restrict__ esrc, const int* __restrict__ edst,
                               const int* __restrict__ etyp, int* __restrict__ cursors,
                               int* __restrict__ perm, int E) {
    int e = blockIdx.x * 256 + threadIdx.x;
    if (e < E) {
        int seg = edst[e] * T_ETYPES + etyp[e];
        int pos = atomicAdd(&cursors[seg], 1);
        perm[pos] = esrc[e];
    }
}

// ---- contention-free target-node sort by type (block-ranked counting sort)
__global__ void thist2(const int* __restrict__ tnt, int* __restrict__ bcnt, int M) {
    __shared__ int h[NT_TYPES];
    if (threadIdx.x < NT_TYPES) h[threadIdx.x] = 0;
    __syncthreads();
    int i = blockIdx.x * 256 + threadIdx.x;
    if (i < M) atomicAdd(&h[tnt[i]], 1);
    __syncthreads();
    if (threadIdx.x < NT_TYPES) bcnt[blockIdx.x * NT_TYPES + threadIdx.x] = h[threadIdx.x];
}

__global__ void tprep2(const int* __restrict__ bcnt, int nb,
                       int* __restrict__ boff, int* __restrict__ gstart,
                       int* __restrict__ endv) {
    __shared__ int sb[128 * NT_TYPES];
    __shared__ int gs[NT_TYPES];
    int tid = threadIdx.x;
    for (int i = tid; i < nb * NT_TYPES; i += blockDim.x) sb[i] = bcnt[i];
    __syncthreads();
    if (tid == 0) {
        int s = 0;
        for (int g = 0; g < NT_TYPES; ++g) {
            int tot = 0;
            for (int b = 0; b < nb; ++b) tot += sb[b * NT_TYPES + g];
            gs[g] = s;
            gstart[g] = s;
            endv[g] = s + tot;
            s += ((tot + 127) >> 7) << 7;     // pad each group to 128-row blocks
        }
        gstart[NT_TYPES] = s;
    }
    __syncthreads();
    if (tid < NT_TYPES) {
        int run = gs[tid];
        for (int b = 0; b < nb; ++b) {
            boff[b * NT_TYPES + tid] = run;
            run += sb[b * NT_TYPES + tid];
        }
    }
}

// tscatter2: local rank via LDS atomics + per-block offset. Any bijection is a
// valid assignment (output values are row-placement-invariant; un-permuted via rowperm).
__global__ void tscatter2(const int* __restrict__ tnt, const int* __restrict__ boff,
                          int* __restrict__ rowperm, int* __restrict__ invperm, int M) {
    __shared__ int h[NT_TYPES];
    if (threadIdx.x < NT_TYPES) h[threadIdx.x] = 0;
    __syncthreads();
    int n = blockIdx.x * 256 + threadIdx.x;
    if (n < M) {
        int g = tnt[n];
        int lr = atomicAdd(&h[g], 1);
        int p = boff[blockIdx.x * NT_TYPES + g] + lr;
        rowperm[p] = n;
        invperm[n] = p;
    }
}

// ---- segment mean -> bf16 A[invperm[dst]][etype*512 + k], swizzled store
__global__ void segmean(const float* __restrict__ x_src, const int* __restrict__ perm,
                        const int* __restrict__ offsets, const int* __restrict__ counts,
                        const int* __restrict__ invperm,
                        unsigned short* __restrict__ A, int nseg) {
    int seg = blockIdx.x * 4 + (threadIdx.x >> 6);
    if (seg >= nseg) return;
    int lane = threadIdx.x & 63;
    int beg = offsets[seg], cnt = counts[seg];
    float4 a0 = make_float4(0.f, 0.f, 0.f, 0.f);
    float4 a1 = make_float4(0.f, 0.f, 0.f, 0.f);
    for (int i = 0; i < cnt; ++i) {
        int s = perm[beg + i];
        const float4* p = reinterpret_cast<const float4*>(x_src + (size_t)s * D);
        float4 v0 = p[lane * 2], v1 = p[lane * 2 + 1];
        a0.x += v0.x; a0.y += v0.y; a0.z += v0.z; a0.w += v0.w;
        a1.x += v1.x; a1.y += v1.y; a1.z += v1.z; a1.w += v1.w;
    }
    float sc = (cnt > 0) ? 1.0f / (float)cnt : 0.0f;
    uint4 u;
    u.x = (unsigned)f2bf(a0.x * sc) | ((unsigned)f2bf(a0.y * sc) << 16);
    u.y = (unsigned)f2bf(a0.z * sc) | ((unsigned)f2bf(a0.w * sc) << 16);
    u.z = (unsigned)f2bf(a1.x * sc) | ((unsigned)f2bf(a1.y * sc) << 16);
    u.w = (unsigned)f2bf(a1.z * sc) | ((unsigned)f2bf(a1.w * sc) << 16);
    int dst = seg >> 3, t = seg & 7;
    int nrow = invperm[dst];
    // logical short-col = t*512 + lane*8; swizzle chunk (lane&7) by row
    int col = t * D + ((lane >> 3) << 6) + (((lane & 7) ^ (nrow & 7)) << 3);
    *reinterpret_cast<uint4*>(A + (size_t)nrow * K_A + col) = u;
}

// ---- fill root slot: A[invperm[n]][4096 + k] = bf16(x_target[n][k]), swizzled
__global__ void rootfill(const float* __restrict__ x_target, const int* __restrict__ invperm,
                         unsigned short* __restrict__ A, int M) {
    int idx = blockIdx.x * 256 + threadIdx.x;
    if (idx >= M * 64) return;
    int n = idx >> 6;
    int q = idx & 63;               // 16B-granule index within the 512-col slot
    const float4* p = reinterpret_cast<const float4*>(x_target + (size_t)n * D + q * 8);
    float4 v0 = p[0], v1 = p[1];
    uint4 u;
    u.x = (unsigned)f2bf(v0.x) | ((unsigned)f2bf(v0.y) << 16);
    u.y = (unsigned)f2bf(v0.z) | ((unsigned)f2bf(v0.w) << 16);
    u.z = (unsigned)f2bf(v1.x) | ((unsigned)f2bf(v1.y) << 16);
    u.w = (unsigned)f2bf(v1.z) | ((unsigned)f2bf(v1.w) << 16);
    int prow = invperm[n];
    int col = K_MAIN + ((q >> 3) << 6) + (((q & 7) ^ (prow & 7)) << 3);
    *reinterpret_cast<uint4*>(A + (size_t)prow * K_A + col) = u;
}

// ---- split-K GEMM, BK=64, swizzle-read fragments (type-sorted rows, K=4608)
__global__ __launch_bounds__(256, 4)
void rgcn_gemm_sk(const unsigned short* __restrict__ A,
                  const unsigned short* __restrict__ WbT,
                  unsigned short* __restrict__ pbuf,
                  const int* __restrict__ gstart, const int* __restrict__ endv,
                  int MBP, int MPc) {
    __shared__ unsigned short As[128 * BK];   // linear [128][64], chunks pre-permuted
    __shared__ unsigned short Bs[128 * BK];
    const int tid = threadIdx.x;

    int d = blockIdx.x;
    int l = d;
    if ((gridDim.x & 7) == 0) {
        int cpx = gridDim.x >> 3;
        l = (d & 7) * cpx + (d >> 3);
    }
    const int nIdx = l & 3;
    const int mz = l >> 2;
    const int mIdx = mz % MBP;
    const int zIdx = mz / MBP;

    const int blockM = mIdx * 128;
    const int blockN = nIdx * 128;
    const int kBase = zIdx * KSPLIT;
    const int g = (blockM >= gstart[1]) + (blockM >= gstart[2]) + (blockM >= gstart[3]);
    const int endRow = endv[g];
    const int rootOff = g * 512;

    const int wid = tid >> 6, lane = tid & 63;
    const int wr = wid >> 1, wc = wid & 1;
    const int lr = lane & 15, lg = lane >> 4;

    f32x4 acc[4][4] = {};

    const unsigned short* Abase = A + (size_t)blockM * K_A + kBase;
    const unsigned short* Bbase = WbT + (size_t)blockN * K_B;

    for (int t = 0; t < KSPLIT / BK; ++t) {
        const int k0 = t * BK;
        const int kc = kBase + k0;
        const int bc = (kc < K_MAIN) ? kc : kc + rootOff;   // uniform per 64-tile
        // stage 128x64 bf16 per matrix: 1024 chunks of 16B, 4 per thread each
#pragma unroll
        for (int q = 0; q < 4; ++q) {
            int c = q * 256 + tid;                 // chunk id: row c>>3, pos c&7
            gl16(Abase + (size_t)(c >> 3) * K_A + k0 + (c & 7) * 8, &As[c * 8]);
        }
#pragma unroll
        for (int q = 0; q < 4; ++q) {
            int c = q * 256 + tid;
            gl16(Bbase + (size_t)(c >> 3) * K_B + bc + (c & 7) * 8, &Bs[c * 8]);
        }
        __syncthreads();

#pragma unroll
        for (int ks = 0; ks < 2; ++ks) {
            bf16x8 a_frag[4], b_frag[4];
#pragma unroll
            for (int mi = 0; mi < 4; ++mi) {
                int r = wr * 64 + mi * 16 + lr;
                a_frag[mi] = *reinterpret_cast<const bf16x8*>(
                    &As[r * BK + (((ks * 4 + lg) ^ (r & 7)) << 3)]);
            }
#pragma unroll
            for (int ni = 0; ni < 4; ++ni) {
                int cR = wc * 64 + ni * 16 + lr;
                b_frag[ni] = *reinterpret_cast<const bf16x8*>(
                    &Bs[cR * BK + (((ks * 4 + lg) ^ (cR & 7)) << 3)]);
            }
#pragma unroll
            for (int mi = 0; mi < 4; ++mi)
#pragma unroll
                for (int ni = 0; ni < 4; ++ni)
                    acc[mi][ni] = __builtin_amdgcn_mfma_f32_16x16x32_bf16(
                        a_frag[mi], b_frag[ni], acc[mi][ni], 0, 0, 0);
        }
        __syncthreads();
    }

#pragma unroll
    for (int mi = 0; mi < 4; ++mi) {
#pragma unroll
        for (int r = 0; r < 4; ++r) {
            int row = blockM + wr * 64 + mi * 16 + lg * 4 + r;
            if (row < endRow) {
#pragma unroll
                for (int ni = 0; ni < 4; ++ni) {
                    int col = blockN + wc * 64 + ni * 16 + lr;
                    pbuf[((size_t)zIdx * MPc + row) * D + col] = f2bf(acc[mi][ni][r]);
                }
            }
        }
    }
}

// ---- reduce splits + per-type bias -> f32 out (un-permute rows)
__global__ void reduce_bias(const unsigned short* __restrict__ pbuf,
                            const int* __restrict__ rowperm, const int* __restrict__ tnt,
                            const float* __restrict__ root_b,
                            float* __restrict__ out, int MPc) {
    int idx = blockIdx.x * 256 + threadIdx.x;   // one per 8 outputs
    if (idx >= MPc * 64) return;
    int nrow = idx >> 6;
    int col = (idx & 63) * 8;
    int orig = rowperm[nrow];
    if (orig < 0) return;
    float s[8] = {0.f, 0.f, 0.f, 0.f, 0.f, 0.f, 0.f, 0.f};
#pragma unroll
    for (int sp = 0; sp < SPLITS; ++sp) {
        uint4 v = *reinterpret_cast<const uint4*>(pbuf + ((size_t)sp * MPc + nrow) * D + col);
        unsigned u[4] = {v.x, v.y, v.z, v.w};
#pragma unroll
        for (int j = 0; j < 4; ++j) {
            s[2 * j]     += bf2f((unsigned short)(u[j] & 0xFFFF));
            s[2 * j + 1] += bf2f((unsigned short)(u[j] >> 16));
        }
    }
    const float* b = root_b + (size_t)tnt[orig] * D + col;
    float4 o0, o1;
    o0.x = s[0] + b[0]; o0.y = s[1] + b[1]; o0.z = s[2] + b[2]; o0.w = s[3] + b[3];
    o1.x = s[4] + b[4]; o1.y = s[5] + b[5]; o1.z = s[6] + b[6]; o1.w = s[7] + b[7];
    float* o = out + (size_t)orig * D + col;
    *reinterpret_cast<float4*>(o) = o0;
    *reinterpret_cast<float4*>(o + 4) = o1;
}

extern "C" void kernel_launch(void* const* d_in, const int* in_sizes, int n_in,
                              void* d_out, int out_size, void* d_ws, size_t ws_size,
                              hipStream_t stream) {
    const float* x_src    = (const float*)d_in[0];
    const float* x_target = (const float*)d_in[1];
    const float* relW     = (const float*)d_in[2];
    const float* rootW    = (const float*)d_in[3];
    const float* rootb    = (const float*)d_in[4];
    const int*   esrc     = (const int*)d_in[5];
    const int*   edst     = (const int*)d_in[6];
    const int*   etyp     = (const int*)d_in[7];
    const int*   tnt      = (const int*)d_in[8];
    float* out = (float*)d_out;

    const int E = in_sizes[5];
    const int M = in_sizes[8];               // n_tgt = 10000
    const int NSEG = M * T_ETYPES;           // 80000
    const int NB = (NSEG + 255) / 256;       // 313
    const int NBT = (M + 255) / 256;         // 40
    const int MBP = (M + 127) / 128 + (NT_TYPES - 1);  // 82
    const int MPc = MBP * 128;               // 10496

    char* ws = (char*)d_ws;
    size_t off = 0;
    unsigned short* Abf = (unsigned short*)(ws + off); off += (size_t)MPc * K_A * 2;        // 96.7 MB
    unsigned short* WbT = (unsigned short*)(ws + off); off += (size_t)D * K_B * 2;          // 6.29 MB
    unsigned short* pb  = (unsigned short*)(ws + off); off += (size_t)SPLITS * MPc * D * 2; // 64.5 MB
    int* counts    = (int*)(ws + off); off += (size_t)NSEG * 4;
    int* partial   = (int*)(ws + off); off += (size_t)NSEG * 4;
    int* offsets   = (int*)(ws + off); off += (size_t)NSEG * 4;
    int* cursors   = (int*)(ws + off); off += (size_t)NSEG * 4;
    int* blockSums = (int*)(ws + off); off += 512 * 4;
    int* perm      = (int*)(ws + off); off += (size_t)E * 4;
    int* bcnt      = (int*)(ws + off); off += (size_t)NBT * NT_TYPES * 4;
    int* boff      = (int*)(ws + off); off += (size_t)NBT * NT_TYPES * 4;
    int* gstart    = (int*)(ws + off); off += 8 * 4;
    int* endv      = (int*)(ws + off); off += 8 * 4;
    int* rowperm   = (int*)(ws + off); off += (size_t)MPc * 4;
    int* invperm   = (int*)(ws + off); off += (size_t)M * 4;

    hipMemsetAsync(counts, 0, (size_t)NSEG * 4, stream);
    hipMemsetAsync(rowperm, 0xFF, (size_t)MPc * 4, stream);

    convert_weights<<<dim3(K_B / 32, D / 32), 256, 0, stream>>>(relW, rootW, WbT);
    // target sort by type (contention-free)
    thist2<<<NBT, 256, 0, stream>>>(tnt, bcnt, M);
    tprep2<<<1, 256, 0, stream>>>(bcnt, NBT, boff, gstart, endv);
    tscatter2<<<NBT, 256, 0, stream>>>(tnt, boff, rowperm, invperm, M);
    // edge sort by (dst, etype)
    hist_kernel<<<(E + 255) / 256, 256, 0, stream>>>(edst, etyp, counts, E);
    scan1<<<NB, 256, 0, stream>>>(counts, partial, blockSums, NSEG);
    scan2<<<1, 512, 0, stream>>>(blockSums, NB);
    scan3<<<NB, 256, 0, stream>>>(partial, blockSums, offsets, cursors, NSEG);
    scatter_kernel<<<(E + 255) / 256, 256, 0, stream>>>(esrc, edst, etyp, cursors, perm, E);
    // build A (type-sorted rows, swizzled layout)
    segmean<<<(NSEG + 3) / 4, 256, 0, stream>>>(x_src, perm, offsets, counts, invperm, Abf, NSEG);
    rootfill<<<(M * 64 + 255) / 256, 256, 0, stream>>>(x_target, invperm, Abf, M);
    // GEMM + reduce
    rgcn_gemm_sk<<<MBP * 4 * SPLITS, 256, 0, stream>>>(Abf, WbT, pb, gstart, endv, MBP, MPc);
    reduce_bias<<<(MPc * 64 + 255) / 256, 256, 0, stream>>>(pb, rowperm, tnt, rootb, out, MPc);
}

// Round 9
// 184.550 us; speedup vs baseline: 1.3469x; 1.0124x over previous
//
#include <hip/hip_runtime.h>
#include <hip/hip_bf16.h>

#define D 512
#define T_ETYPES 8
#define NT_TYPES 4
#define K_MAIN 4096   // T_ETYPES * D
#define K_A 4608      // A row stride: 4096 msg cols + 512 root cols (type-specific)
#define K_B 6144      // WbT row stride: 4096 rel + 4*512 root windows
#define SPLITS 6
#define KSPLIT 768    // K_A / SPLITS (12 tiles of 64)
#define BK 64         // K-tile per barrier

// Swizzle: within each aligned 64-col (128B) tile of a row, the 16B chunk with
// logical index j (0..7) is stored at position j ^ (row & 7). Producers
// (segmean/rootfill/convert_weights) write swizzled; global_load_lds copies
// linearly; the GEMM fragment read applies the same XOR.

typedef __attribute__((ext_vector_type(8))) short bf16x8;
typedef __attribute__((ext_vector_type(4))) float f32x4;

__device__ __forceinline__ unsigned short f2bf(float f) {
    union { float f; unsigned u; } u{f};
    unsigned r = u.u + 0x7FFF + ((u.u >> 16) & 1);   // RNE
    return (unsigned short)(r >> 16);
}
__device__ __forceinline__ float bf2f(unsigned short h) {
    union { unsigned u; float f; } v{(unsigned)h << 16};
    return v.f;
}

__device__ __forceinline__ void gl16(const unsigned short* g, unsigned short* l) {
    __builtin_amdgcn_global_load_lds(
        (const __attribute__((address_space(1))) unsigned int*)g,
        (__attribute__((address_space(3))) unsigned int*)l,
        16, 0, 0);
}

// ---- one-time weight prep (swizzled store): logical WbT[o][c]
__global__ void convert_weights(const float* __restrict__ relW,
                                const float* __restrict__ rootW,
                                unsigned short* __restrict__ WbT) {
    __shared__ float tile[32][33];
    int c0 = blockIdx.x * 32;
    int o0 = blockIdx.y * 32;
    int tid = threadIdx.x;
#pragma unroll
    for (int it = 0; it < 4; ++it) {
        int idx = it * 256 + tid;
        int oc = idx & 31, cc = idx >> 5;
        int c = c0 + cc, o = o0 + oc;
        float v = (c < K_MAIN) ? relW[(size_t)c * D + o]
                               : rootW[(size_t)(c - K_MAIN) * D + o];
        tile[cc][oc] = v;
    }
    __syncthreads();
#pragma unroll
    for (int it = 0; it < 4; ++it) {
        int idx = it * 256 + tid;
        int cc = idx & 31, oc = idx >> 5;
        int o = o0 + oc, c = c0 + cc;
        int csw = (c & ~63) | (((((c >> 3) & 7) ^ (o & 7))) << 3) | (c & 7);
        WbT[(size_t)o * K_B + csw] = f2bf(tile[cc][oc]);
    }
}

// ---- edge sort by seg = dst*8+etype: histogram -> scan -> scatter
__global__ void hist_kernel(const int* __restrict__ edst, const int* __restrict__ etyp,
                            int* __restrict__ counts, int E) {
    int e = blockIdx.x * 256 + threadIdx.x;
    if (e < E) atomicAdd(&counts[edst[e] * T_ETYPES + etyp[e]], 1);
}

__global__ void scan1(const int* __restrict__ counts, int* __restrict__ partial,
                      int* __restrict__ blockSums, int n) {
    __shared__ int sh[256];
    int tid = threadIdx.x, i = blockIdx.x * 256 + tid;
    int c = (i < n) ? counts[i] : 0;
    int val = c;
    sh[tid] = val; __syncthreads();
#pragma unroll
    for (int off = 1; off < 256; off <<= 1) {
        int add = (tid >= off) ? sh[tid - off] : 0;
        __syncthreads();
        val += add; sh[tid] = val;
        __syncthreads();
    }
    if (i < n) partial[i] = val - c;
    if (tid == 255) blockSums[blockIdx.x] = val;
}

__global__ void scan2(int* __restrict__ blockSums, int nb) {
    __shared__ int sh[512];
    int tid = threadIdx.x;
    int c = (tid < nb) ? blockSums[tid] : 0;
    int val = c;
    sh[tid] = val; __syncthreads();
#pragma unroll
    for (int off = 1; off < 512; off <<= 1) {
        int add = (tid >= off) ? sh[tid - off] : 0;
        __syncthreads();
        val += add; sh[tid] = val;
        __syncthreads();
    }
    if (tid < nb) blockSums[tid] = val - c;
}

__global__ void scan3(const int* __restrict__ partial, const int* __restrict__ blockSums,
                      int* __restrict__ offsets, int* __restrict__ cursors, int n) {
    int i = blockIdx.x * 256 + threadIdx.x;
    if (i < n) {
        int v = partial[i] + blockSums[i >> 8];
        offsets[i] = v;
        cursors[i] = v;
    }
}

__global__ void scatter_kernel(const int* __restrict__ esrc, const int* __restrict__ edst,
                               const int* __restrict__ etyp, int* __restrict__ cursors,
                               int* __restrict__ perm, int E) {
    int e = blockIdx.x * 256 + threadIdx.x;
    if (e < E) {
        int seg = edst[e] * T_ETYPES + etyp[e];
        int pos = atomicAdd(&cursors[seg], 1);
        perm[pos] = esrc[e];
    }
}

// ---- contention-free target-node sort by type (block-ranked counting sort)
__global__ void thist2(const int* __restrict__ tnt, int* __restrict__ bcnt, int M) {
    __shared__ int h[NT_TYPES];
    if (threadIdx.x < NT_TYPES) h[threadIdx.x] = 0;
    __syncthreads();
    int i = blockIdx.x * 256 + threadIdx.x;
    if (i < M) atomicAdd(&h[tnt[i]], 1);
    __syncthreads();
    if (threadIdx.x < NT_TYPES) bcnt[blockIdx.x * NT_TYPES + threadIdx.x] = h[threadIdx.x];
}

__global__ void tprep2(const int* __restrict__ bcnt, int nb,
                       int* __restrict__ boff, int* __restrict__ gstart,
                       int* __restrict__ endv) {
    __shared__ int sb[128 * NT_TYPES];
    __shared__ int gs[NT_TYPES];
    int tid = threadIdx.x;
    for (int i = tid; i < nb * NT_TYPES; i += blockDim.x) sb[i] = bcnt[i];
    __syncthreads();
    if (tid == 0) {
        int s = 0;
        for (int g = 0; g < NT_TYPES; ++g) {
            int tot = 0;
            for (int b = 0; b < nb; ++b) tot += sb[b * NT_TYPES + g];
            gs[g] = s;
            gstart[g] = s;
            endv[g] = s + tot;
            s += ((tot + 127) >> 7) << 7;
        }
        gstart[NT_TYPES] = s;
    }
    __syncthreads();
    if (tid < NT_TYPES) {
        int run = gs[tid];
        for (int b = 0; b < nb; ++b) {
            boff[b * NT_TYPES + tid] = run;
            run += sb[b * NT_TYPES + tid];
        }
    }
}

__global__ void tscatter2(const int* __restrict__ tnt, const int* __restrict__ boff,
                          int* __restrict__ rowperm, int* __restrict__ invperm, int M) {
    __shared__ int h[NT_TYPES];
    if (threadIdx.x < NT_TYPES) h[threadIdx.x] = 0;
    __syncthreads();
    int n = blockIdx.x * 256 + threadIdx.x;
    if (n < M) {
        int g = tnt[n];
        int lr = atomicAdd(&h[g], 1);
        int p = boff[blockIdx.x * NT_TYPES + g] + lr;
        rowperm[p] = n;
        invperm[n] = p;
    }
}

// ---- fused: segment mean (unroll-2) + root-slot fill, both swizzled into A
__global__ void build_A(const float* __restrict__ x_src, const int* __restrict__ perm,
                        const int* __restrict__ offsets, const int* __restrict__ counts,
                        const int* __restrict__ invperm, const float* __restrict__ x_target,
                        unsigned short* __restrict__ A, int nseg, int segBlocks, int M) {
    if ((int)blockIdx.x >= segBlocks) {
        // ---- rootfill part: one 16B granule per thread
        int idx = ((int)blockIdx.x - segBlocks) * 256 + threadIdx.x;
        if (idx >= M * 64) return;
        int n = idx >> 6;
        int q = idx & 63;
        const float4* p = reinterpret_cast<const float4*>(x_target + (size_t)n * D + q * 8);
        float4 v0 = p[0], v1 = p[1];
        uint4 u;
        u.x = (unsigned)f2bf(v0.x) | ((unsigned)f2bf(v0.y) << 16);
        u.y = (unsigned)f2bf(v0.z) | ((unsigned)f2bf(v0.w) << 16);
        u.z = (unsigned)f2bf(v1.x) | ((unsigned)f2bf(v1.y) << 16);
        u.w = (unsigned)f2bf(v1.z) | ((unsigned)f2bf(v1.w) << 16);
        int prow = invperm[n];
        int col = K_MAIN + ((q >> 3) << 6) + (((q & 7) ^ (prow & 7)) << 3);
        *reinterpret_cast<uint4*>(A + (size_t)prow * K_A + col) = u;
        return;
    }
    int seg = blockIdx.x * 4 + (threadIdx.x >> 6);
    if (seg >= nseg) return;
    int lane = threadIdx.x & 63;
    int beg = offsets[seg], cnt = counts[seg];
    float4 a0 = make_float4(0.f, 0.f, 0.f, 0.f);
    float4 a1 = make_float4(0.f, 0.f, 0.f, 0.f);
    float4 b0 = make_float4(0.f, 0.f, 0.f, 0.f);
    float4 b1 = make_float4(0.f, 0.f, 0.f, 0.f);
    int i = 0;
    for (; i + 2 <= cnt; i += 2) {     // unroll-2: two independent load chains
        int s0 = perm[beg + i], s1 = perm[beg + i + 1];
        const float4* p0 = reinterpret_cast<const float4*>(x_src + (size_t)s0 * D);
        const float4* p1 = reinterpret_cast<const float4*>(x_src + (size_t)s1 * D);
        float4 x0 = p0[lane * 2], x1 = p0[lane * 2 + 1];
        float4 y0 = p1[lane * 2], y1 = p1[lane * 2 + 1];
        a0.x += x0.x; a0.y += x0.y; a0.z += x0.z; a0.w += x0.w;
        a1.x += x1.x; a1.y += x1.y; a1.z += x1.z; a1.w += x1.w;
        b0.x += y0.x; b0.y += y0.y; b0.z += y0.z; b0.w += y0.w;
        b1.x += y1.x; b1.y += y1.y; b1.z += y1.z; b1.w += y1.w;
    }
    if (i < cnt) {
        int s = perm[beg + i];
        const float4* p = reinterpret_cast<const float4*>(x_src + (size_t)s * D);
        float4 v0 = p[lane * 2], v1 = p[lane * 2 + 1];
        a0.x += v0.x; a0.y += v0.y; a0.z += v0.z; a0.w += v0.w;
        a1.x += v1.x; a1.y += v1.y; a1.z += v1.z; a1.w += v1.w;
    }
    a0.x += b0.x; a0.y += b0.y; a0.z += b0.z; a0.w += b0.w;
    a1.x += b1.x; a1.y += b1.y; a1.z += b1.z; a1.w += b1.w;
    float sc = (cnt > 0) ? 1.0f / (float)cnt : 0.0f;
    uint4 u;
    u.x = (unsigned)f2bf(a0.x * sc) | ((unsigned)f2bf(a0.y * sc) << 16);
    u.y = (unsigned)f2bf(a0.z * sc) | ((unsigned)f2bf(a0.w * sc) << 16);
    u.z = (unsigned)f2bf(a1.x * sc) | ((unsigned)f2bf(a1.y * sc) << 16);
    u.w = (unsigned)f2bf(a1.z * sc) | ((unsigned)f2bf(a1.w * sc) << 16);
    int dst = seg >> 3, t = seg & 7;
    int nrow = invperm[dst];
    int col = t * D + ((lane >> 3) << 6) + (((lane & 7) ^ (nrow & 7)) << 3);
    *reinterpret_cast<uint4*>(A + (size_t)nrow * K_A + col) = u;
}

// ---- split-K GEMM, 128x256 tile, 512 threads (8 waves), BK=64, swizzle-read
__global__ __launch_bounds__(512, 4)
void rgcn_gemm_sk(const unsigned short* __restrict__ A,
                  const unsigned short* __restrict__ WbT,
                  unsigned short* __restrict__ pbuf,
                  const int* __restrict__ gstart, const int* __restrict__ endv,
                  int MBP, int MPc) {
    __shared__ unsigned short As[128 * BK];   // 16 KB
    __shared__ unsigned short Bs[256 * BK];   // 32 KB
    const int tid = threadIdx.x;

    int d = blockIdx.x;
    int l = d;
    if ((gridDim.x & 7) == 0) {
        int cpx = gridDim.x >> 3;
        l = (d & 7) * cpx + (d >> 3);
    }
    const int nIdx = l & 1;
    const int mz = l >> 1;
    const int mIdx = mz % MBP;
    const int zIdx = mz / MBP;

    const int blockM = mIdx * 128;
    const int blockN = nIdx * 256;
    const int kBase = zIdx * KSPLIT;
    const int g = (blockM >= gstart[1]) + (blockM >= gstart[2]) + (blockM >= gstart[3]);
    const int endRow = endv[g];
    const int rootOff = g * 512;

    const int wid = tid >> 6, lane = tid & 63;
    const int wr = wid >> 2, wc = wid & 3;     // 2 x 4 wave grid, 64x64 out each
    const int lr = lane & 15, lg = lane >> 4;

    f32x4 acc[4][4] = {};

    const unsigned short* Abase = A + (size_t)blockM * K_A + kBase;
    const unsigned short* Bbase = WbT + (size_t)blockN * K_B;

    for (int t = 0; t < KSPLIT / BK; ++t) {
        const int k0 = t * BK;
        const int kc = kBase + k0;
        const int bc = (kc < K_MAIN) ? kc : kc + rootOff;   // uniform per 64-tile
        // A: 1024 chunks (2/thread); B: 2048 chunks (4/thread); chunk = row c>>3, pos c&7
#pragma unroll
        for (int q = 0; q < 2; ++q) {
            int c = q * 512 + tid;
            gl16(Abase + (size_t)(c >> 3) * K_A + k0 + (c & 7) * 8, &As[c * 8]);
        }
#pragma unroll
        for (int q = 0; q < 4; ++q) {
            int c = q * 512 + tid;
            gl16(Bbase + (size_t)(c >> 3) * K_B + bc + (c & 7) * 8, &Bs[c * 8]);
        }
        __syncthreads();

#pragma unroll
        for (int ks = 0; ks < 2; ++ks) {
            bf16x8 a_frag[4], b_frag[4];
#pragma unroll
            for (int mi = 0; mi < 4; ++mi) {
                int r = wr * 64 + mi * 16 + lr;
                a_frag[mi] = *reinterpret_cast<const bf16x8*>(
                    &As[r * BK + (((ks * 4 + lg) ^ (r & 7)) << 3)]);
            }
#pragma unroll
            for (int ni = 0; ni < 4; ++ni) {
                int cR = wc * 64 + ni * 16 + lr;
                b_frag[ni] = *reinterpret_cast<const bf16x8*>(
                    &Bs[cR * BK + (((ks * 4 + lg) ^ (cR & 7)) << 3)]);
            }
#pragma unroll
            for (int mi = 0; mi < 4; ++mi)
#pragma unroll
                for (int ni = 0; ni < 4; ++ni)
                    acc[mi][ni] = __builtin_amdgcn_mfma_f32_16x16x32_bf16(
                        a_frag[mi], b_frag[ni], acc[mi][ni], 0, 0, 0);
        }
        __syncthreads();
    }

#pragma unroll
    for (int mi = 0; mi < 4; ++mi) {
#pragma unroll
        for (int r = 0; r < 4; ++r) {
            int row = blockM + wr * 64 + mi * 16 + lg * 4 + r;
            if (row < endRow) {
#pragma unroll
                for (int ni = 0; ni < 4; ++ni) {
                    int col = blockN + wc * 64 + ni * 16 + lr;
                    pbuf[((size_t)zIdx * MPc + row) * D + col] = f2bf(acc[mi][ni][r]);
                }
            }
        }
    }
}

// ---- reduce splits + per-type bias -> f32 out (un-permute rows)
__global__ void reduce_bias(const unsigned short* __restrict__ pbuf,
                            const int* __restrict__ rowperm, const int* __restrict__ tnt,
                            const float* __restrict__ root_b,
                            float* __restrict__ out, int MPc) {
    int idx = blockIdx.x * 256 + threadIdx.x;
    if (idx >= MPc * 64) return;
    int nrow = idx >> 6;
    int col = (idx & 63) * 8;
    int orig = rowperm[nrow];
    if (orig < 0) return;
    float s[8] = {0.f, 0.f, 0.f, 0.f, 0.f, 0.f, 0.f, 0.f};
#pragma unroll
    for (int sp = 0; sp < SPLITS; ++sp) {
        uint4 v = *reinterpret_cast<const uint4*>(pbuf + ((size_t)sp * MPc + nrow) * D + col);
        unsigned u[4] = {v.x, v.y, v.z, v.w};
#pragma unroll
        for (int j = 0; j < 4; ++j) {
            s[2 * j]     += bf2f((unsigned short)(u[j] & 0xFFFF));
            s[2 * j + 1] += bf2f((unsigned short)(u[j] >> 16));
        }
    }
    const float* b = root_b + (size_t)tnt[orig] * D + col;
    float4 o0, o1;
    o0.x = s[0] + b[0]; o0.y = s[1] + b[1]; o0.z = s[2] + b[2]; o0.w = s[3] + b[3];
    o1.x = s[4] + b[4]; o1.y = s[5] + b[5]; o1.z = s[6] + b[6]; o1.w = s[7] + b[7];
    float* o = out + (size_t)orig * D + col;
    *reinterpret_cast<float4*>(o) = o0;
    *reinterpret_cast<float4*>(o + 4) = o1;
}

extern "C" void kernel_launch(void* const* d_in, const int* in_sizes, int n_in,
                              void* d_out, int out_size, void* d_ws, size_t ws_size,
                              hipStream_t stream) {
    const float* x_src    = (const float*)d_in[0];
    const float* x_target = (const float*)d_in[1];
    const float* relW     = (const float*)d_in[2];
    const float* rootW    = (const float*)d_in[3];
    const float* rootb    = (const float*)d_in[4];
    const int*   esrc     = (const int*)d_in[5];
    const int*   edst     = (const int*)d_in[6];
    const int*   etyp     = (const int*)d_in[7];
    const int*   tnt      = (const int*)d_in[8];
    float* out = (float*)d_out;

    const int E = in_sizes[5];
    const int M = in_sizes[8];               // n_tgt = 10000
    const int NSEG = M * T_ETYPES;           // 80000
    const int NB = (NSEG + 255) / 256;       // 313
    const int NBT = (M + 255) / 256;         // 40
    const int MBP = (M + 127) / 128 + (NT_TYPES - 1);  // 82
    const int MPc = MBP * 128;               // 10496
    const int segBlocks = (NSEG + 3) / 4;    // 20000
    const int rootBlocks = (M * 64 + 255) / 256;       // 2500

    char* ws = (char*)d_ws;
    size_t off = 0;
    unsigned short* Abf = (unsigned short*)(ws + off); off += (size_t)MPc * K_A * 2;        // 96.7 MB
    unsigned short* WbT = (unsigned short*)(ws + off); off += (size_t)D * K_B * 2;          // 6.29 MB
    unsigned short* pb  = (unsigned short*)(ws + off); off += (size_t)SPLITS * MPc * D * 2; // 64.5 MB
    int* counts    = (int*)(ws + off); off += (size_t)NSEG * 4;
    int* partial   = (int*)(ws + off); off += (size_t)NSEG * 4;
    int* offsets   = (int*)(ws + off); off += (size_t)NSEG * 4;
    int* cursors   = (int*)(ws + off); off += (size_t)NSEG * 4;
    int* blockSums = (int*)(ws + off); off += 512 * 4;
    int* perm      = (int*)(ws + off); off += (size_t)E * 4;
    int* bcnt      = (int*)(ws + off); off += (size_t)NBT * NT_TYPES * 4;
    int* boff      = (int*)(ws + off); off += (size_t)NBT * NT_TYPES * 4;
    int* gstart    = (int*)(ws + off); off += 8 * 4;
    int* endv      = (int*)(ws + off); off += 8 * 4;
    int* rowperm   = (int*)(ws + off); off += (size_t)MPc * 4;
    int* invperm   = (int*)(ws + off); off += (size_t)M * 4;

    hipMemsetAsync(counts, 0, (size_t)NSEG * 4, stream);
    hipMemsetAsync(rowperm, 0xFF, (size_t)MPc * 4, stream);

    convert_weights<<<dim3(K_B / 32, D / 32), 256, 0, stream>>>(relW, rootW, WbT);
    // target sort by type (contention-free)
    thist2<<<NBT, 256, 0, stream>>>(tnt, bcnt, M);
    tprep2<<<1, 256, 0, stream>>>(bcnt, NBT, boff, gstart, endv);
    tscatter2<<<NBT, 256, 0, stream>>>(tnt, boff, rowperm, invperm, M);
    // edge sort by (dst, etype)
    hist_kernel<<<(E + 255) / 256, 256, 0, stream>>>(edst, etyp, counts, E);
    scan1<<<NB, 256, 0, stream>>>(counts, partial, blockSums, NSEG);
    scan2<<<1, 512, 0, stream>>>(blockSums, NB);
    scan3<<<NB, 256, 0, stream>>>(partial, blockSums, offsets, cursors, NSEG);
    scatter_kernel<<<(E + 255) / 256, 256, 0, stream>>>(esrc, edst, etyp, cursors, perm, E);
    // build A (segmean unroll-2 + rootfill fused, swizzled layout)
    build_A<<<segBlocks + rootBlocks, 256, 0, stream>>>(
        x_src, perm, offsets, counts, invperm, x_target, Abf, NSEG, segBlocks, M);
    // GEMM (128x256 tile, 512 threads) + reduce
    rgcn_gemm_sk<<<MBP * 2 * SPLITS, 512, 0, stream>>>(Abf, WbT, pb, gstart, endv, MBP, MPc);
    reduce_bias<<<(MPc * 64 + 255) / 256, 256, 0, stream>>>(pb, rowperm, tnt, rootb, out, MPc);
}